// Round 1
// baseline (390.315 us; speedup 1.0000x reference)
//
#include <hip/hip_runtime.h>
#include <hip/hip_bf16.h>

using bf16 = __hip_bfloat16;
typedef __bf16 bfrag __attribute__((ext_vector_type(8)));
typedef float  ffrag __attribute__((ext_vector_type(4)));

// Problem: B=32, N=8, Q=1536, K=256, CELL=128, EMB=32. Inputs f32, outputs f32.
// workspace layout (bytes)
#define WS_EO    0         // emb_o bf16 [256 key][32 e]                16 KB
#define WS_W2T   16384     // Wq2^T bf16 [32 e][256 h]                  16 KB
#define WS_W1T   32768     // Wq1^T bf16 [256 h][32 in-pad] (+bias k15) 16 KB
#define WS_WA1T  49152     // Wa1^T*ln2 bf16 [64 u][32 e]                4 KB
#define WS_VBF   65536     // view_cell bf16 [256 bn][128 c][256 k]     16 MB (optional)

#define LOG2E 1.44269504f
#define LN2   0.6931471805599453f

__device__ __forceinline__ float sigmoidf_(float x){ return 1.f/(1.f+__expf(-x)); }

__device__ __forceinline__ void relpose(const float* mo, const float* mq, float* o) {
  float a=mo[0],bb=mo[1],c=mo[2], d=mo[4],e=mo[5],f=mo[6], g=mo[8],h=mo[9],i9=mo[10];
  float A = e*i9-f*h, Bc = f*g-d*i9, C = d*h-e*g;
  float inv = 1.f/(a*A + bb*Bc + c*C);
  float r00=A*inv,  r01=(c*h-bb*i9)*inv, r02=(bb*f-c*e)*inv;
  float r10=Bc*inv, r11=(a*i9-c*g)*inv,  r12=(c*d-a*f)*inv;
  float r20=C*inv,  r21=(bb*g-a*h)*inv,  r22=(a*e-bb*d)*inv;
  float tx = mq[3]-mo[3], ty = mq[7]-mo[7], tz = mq[11]-mo[11];
  o[0]=r00*mq[0]+r01*mq[4]+r02*mq[8];  o[1]=r00*mq[1]+r01*mq[5]+r02*mq[9];
  o[2]=r00*mq[2]+r01*mq[6]+r02*mq[10]; o[3]=r00*tx+r01*ty+r02*tz;
  o[4]=r10*mq[0]+r11*mq[4]+r12*mq[8];  o[5]=r10*mq[1]+r11*mq[5]+r12*mq[9];
  o[6]=r10*mq[2]+r11*mq[6]+r12*mq[10]; o[7]=r10*tx+r11*ty+r12*tz;
  o[8]=r20*mq[0]+r21*mq[4]+r22*mq[8];  o[9]=r20*mq[1]+r21*mq[5]+r22*mq[9];
  o[10]=r20*mq[2]+r21*mq[6]+r22*mq[10]; o[11]=r20*tx+r21*ty+r22*tz;
}

__device__ __forceinline__ void quat7(const float* m, float* o) {
  float m00=m[0], m01=m[1], m02=m[2];
  float m10=m[4], m11=m[5], m12=m[6];
  float m20=m[8], m21=m[9], m22=m[10];
  float t,q0,q1,q2,q3;
  if (m22 < 0.f) {
    if (m00 > m11) { t=1.f+m00-m11-m22; q0=t;        q1=m01+m10; q2=m20+m02; q3=m12-m21; }
    else           { t=1.f-m00+m11-m22; q0=m01+m10; q1=t;        q2=m12+m21; q3=m20-m02; }
  } else {
    if (m00 < -m11){ t=1.f-m00-m11+m22; q0=m20+m02; q1=m12+m21; q2=t;        q3=m01-m10; }
    else           { t=1.f+m00+m11+m22; q0=m12-m21; q1=m20-m02; q2=m01-m10; q3=t;        }
  }
  float s = 0.5f / sqrtf(t);
  o[0]=m[3]; o[1]=m[7]; o[2]=m[11];
  o[3]=q0*s; o[4]=q1*s; o[5]=q2*s; o[6]=q3*s;
}

// ---------------- single prep kernel: vconv blocks + 5 parallel 1-block roles --------
__global__ void k_prep(const float* __restrict__ vc, bf16* __restrict__ vbf,
                       const float* __restrict__ pose_o, const float* __restrict__ pose_q,
                       const float* __restrict__ Wk1, const float* __restrict__ bk1,
                       const float* __restrict__ Wk2, const float* __restrict__ bk2,
                       const float* __restrict__ Wq1, const float* __restrict__ bq1,
                       const float* __restrict__ Wq2, const float* __restrict__ Wa1,
                       float* __restrict__ out_qo, float* __restrict__ out_qq,
                       bf16* __restrict__ ws_eo, bf16* __restrict__ ws_w2t,
                       bf16* __restrict__ ws_w1t, bf16* __restrict__ ws_wa1t,
                       int vblocks) {
  const int bid = blockIdx.x, tid = threadIdx.x;
  if (bid < vblocks) {   // view_cell f32 -> bf16
    int idx = (bid*256 + tid)*8;
    float4 a = *(const float4*)&vc[idx];
    float4 b = *(const float4*)&vc[idx+4];
    __bf16 o[8] __attribute__((aligned(16)));
    o[0]=(__bf16)a.x; o[1]=(__bf16)a.y; o[2]=(__bf16)a.z; o[3]=(__bf16)a.w;
    o[4]=(__bf16)b.x; o[5]=(__bf16)b.y; o[6]=(__bf16)b.z; o[7]=(__bf16)b.w;
    *(uint4*)&vbf[idx] = *(const uint4*)o;
    return;
  }
  const int role = bid - vblocks;
  if (role == 0) {          // quaternion outputs
    float mo[12];
    #pragma unroll
    for (int i=0;i<12;i++) mo[i] = pose_o[tid*12+i];
    float q7[7]; quat7(mo, q7);
    #pragma unroll
    for (int i=0;i<7;i++) out_qo[tid*7+i] = q7[i];
    if (tid < 32) {
      float mq[12];
      #pragma unroll
      for (int i=0;i<12;i++) mq[i] = pose_q[tid*12+i];
      float q7b[7]; quat7(mq, q7b);
      #pragma unroll
      for (int i=0;i<7;i++) out_qq[tid*7+i] = q7b[i];
    }
  } else if (role == 1) {   // key embeddings -> ws_eo [key][32]
    int k = tid;
    float x0 = -1.f + (float)(k>>4)*(2.f/15.f);
    float x1 = -1.f + (float)(k&15)*(2.f/15.f);
    float acc[32];
    #pragma unroll
    for (int e=0;e<32;e++) acc[e] = bk2[e];
    for (int j=0;j<128;j++) {
      float hj = fmaxf(fmaf(x0, Wk1[j], fmaf(x1, Wk1[128+j], bk1[j])), 0.f);
      #pragma unroll
      for (int u=0;u<8;u++) {
        float4 w = *(const float4*)&Wk2[j*32+u*4];
        acc[u*4+0] = fmaf(hj, w.x, acc[u*4+0]);
        acc[u*4+1] = fmaf(hj, w.y, acc[u*4+1]);
        acc[u*4+2] = fmaf(hj, w.z, acc[u*4+2]);
        acc[u*4+3] = fmaf(hj, w.w, acc[u*4+3]);
      }
    }
    #pragma unroll
    for (int e=0;e<32;e++) ws_eo[k*32+e] = __float2bfloat16(acc[e]);
  } else if (role == 2) {   // Wq2 [256h][32e] -> ws_w2t [e][h]
    int k = tid;
    #pragma unroll
    for (int u=0;u<8;u++) {
      float4 w = *(const float4*)&Wq2[k*32+u*4];
      ws_w2t[(u*4+0)*256+k] = __float2bfloat16(w.x);
      ws_w2t[(u*4+1)*256+k] = __float2bfloat16(w.y);
      ws_w2t[(u*4+2)*256+k] = __float2bfloat16(w.z);
      ws_w2t[(u*4+3)*256+k] = __float2bfloat16(w.w);
    }
  } else if (role == 3) {   // Wq1 [15][256] -> ws_w1t [h][32] with bias row k=15, 16..31 = 0
    int h = tid;
    bf16 row[32];
    #pragma unroll
    for (int i=0;i<15;i++) row[i] = __float2bfloat16(Wq1[i*256+h]);
    row[15] = __float2bfloat16(bq1[h]);
    #pragma unroll
    for (int i=16;i<32;i++) row[i] = __float2bfloat16(0.f);
    #pragma unroll
    for (int i=0;i<32;i++) ws_w1t[h*32+i] = row[i];
  } else {                  // Wa1 [32e][64u] -> ws_wa1t [u][e] * ln2 (emb is log2e-scaled)
    if (tid < 64) {
      #pragma unroll
      for (int e=0;e<32;e++) ws_wa1t[tid*32+e] = __float2bfloat16(Wa1[e*64+tid] * LN2);
    }
  }
}

// ---------------- k_main: one wave per 32-q tile, zero barriers in n-loop ------------
// grid: 1536 one-wave blocks, id = qt*32 + b  (=> XCD(id%8) == b&7: V[b] L2-local).
// Frag layouts (gfx950 16x16x32_bf16): A[m=l15][k=quad*8+j], B[k=quad*8+j][n=l15],
// D[m=quad*4+r][n=l15]. All LDS transposes are wave-local (lgkmcnt-ordered only).
template<bool PRE>
__global__ void __launch_bounds__(64, 2)
k_main(const float* __restrict__ vc, const bf16* __restrict__ vbf_,
       const float* __restrict__ pose_o, const float* __restrict__ pose_q,
       const bf16* __restrict__ ws_eo_, const bf16* __restrict__ ws_w2t_,
       const bf16* __restrict__ ws_w1t_, const bf16* __restrict__ ws_wa1t_,
       const float* __restrict__ bq2,
       const float* __restrict__ ba1, const float* __restrict__ Wa2,
       const float* __restrict__ ba2,
       float* __restrict__ out) {
  __shared__ __align__(16) __bf16 s_hp[32*264];   // hidden [q][h] then expP [q][key] 16.9 KB
  __shared__ __align__(16) __bf16 s_eq[32*40];    // emb_q'  [q][e]                   2.5 KB
  __shared__ __align__(16) float  s_pt[96];       // relpose [8][12]

  const __bf16* vbf  = (const __bf16*)vbf_;
  const __bf16* eo   = (const __bf16*)ws_eo_;
  const __bf16* w2t  = (const __bf16*)ws_w2t_;
  const __bf16* w1t  = (const __bf16*)ws_w1t_;
  const __bf16* wa1t = (const __bf16*)ws_wa1t_;

  const int lane = threadIdx.x;       // 64-thread block = 1 wave
  const int quad = lane >> 4;
  const int l15  = lane & 15;
  const int b    = blockIdx.x & 31;
  const int qt0  = (blockIdx.x >> 5) * 32;

  // ---- one-time staging (only barrier in the kernel) ----
  if (lane < 8) {
    float mo[12], mq[12], pt[12];
    #pragma unroll
    for (int i=0;i<12;i++) mo[i] = pose_o[(b*8+lane)*12+i];
    #pragma unroll
    for (int i=0;i<12;i++) mq[i] = pose_q[b*12+i];
    relpose(mo, mq, pt);
    #pragma unroll
    for (int i=0;i<12;i++) s_pt[lane*12+i] = pt[i];
  }
  __syncthreads();

  // ---- hoisted per-lane constants ----
  float c012[2][3];
  #pragma unroll
  for (int qs=0;qs<2;qs++) {
    int qg = qt0 + qs*16 + l15;
    c012[qs][0] = (float)(qg>>8) * 0.2f;
    c012[qs][1] = -1.f + (float)((qg>>4)&15)*(2.f/15.f);
    c012[qs][2] = -1.f + (float)(qg&15)*(2.f/15.f);
  }
  const float bq2s0 = bq2[l15]    * LOG2E;
  const float bq2s1 = bq2[16+l15] * LOG2E;
  const float ba2v  = ba2[0];

  ffrag acc[8][2];
  #pragma unroll
  for (int ct=0;ct<8;ct++) {
    acc[ct][0] = (ffrag){0.f,0.f,0.f,0.f};
    acc[ct][1] = (ffrag){0.f,0.f,0.f,0.f};
  }

  #pragma unroll 1
  for (int n=0; n<8; n++) {
    const int bn = b*8 + n;
    // ---- phase 1: hidden D[h][q] = W1^T @ X (K=32), all 16 h-tiles, wave-local ----
    {
      float4 pa = *(const float4*)&s_pt[n*12];
      float4 pb = *(const float4*)&s_pt[n*12+4];
      float4 pc = *(const float4*)&s_pt[n*12+8];
      bfrag Bx[2];
      #pragma unroll
      for (int qs=0;qs<2;qs++) {
        bfrag x;
        if (quad == 0) {
          x[0]=(__bf16)pa.x; x[1]=(__bf16)pa.y; x[2]=(__bf16)pa.z; x[3]=(__bf16)pa.w;
          x[4]=(__bf16)pb.x; x[5]=(__bf16)pb.y; x[6]=(__bf16)pb.z; x[7]=(__bf16)pb.w;
        } else if (quad == 1) {
          x[0]=(__bf16)pc.x; x[1]=(__bf16)pc.y; x[2]=(__bf16)pc.z; x[3]=(__bf16)pc.w;
          x[4]=(__bf16)c012[qs][0]; x[5]=(__bf16)c012[qs][1];
          x[6]=(__bf16)c012[qs][2]; x[7]=(__bf16)1.f;
        } else {
          #pragma unroll
          for (int j=0;j<8;j++) x[j]=(__bf16)0.f;
        }
        Bx[qs] = x;
      }
      #pragma unroll
      for (int t=0;t<16;t++) {
        bfrag A = *(const bfrag*)&w1t[(t*16+l15)*32 + quad*8];
        #pragma unroll
        for (int qs=0;qs<2;qs++) {
          ffrag C = {0.f,0.f,0.f,0.f};
          C = __builtin_amdgcn_mfma_f32_16x16x32_bf16(A, Bx[qs], C, 0, 0, 0);
          __bf16 p[4] __attribute__((aligned(8)));
          #pragma unroll
          for (int r=0;r<4;r++) p[r] = (__bf16)fmaxf(C[r], 0.f);
          *(uint2*)&s_hp[(qs*16+l15)*264 + t*16 + quad*4] = *(const uint2*)p;
        }
      }
    }
    // ---- phase 2: emb'[q][e] = (hidden @ W2 + bq2) * log2e, full K=256, wave-local ----
    {
      ffrag C2[2][2];   // [qs][et]
      C2[0][0]=(ffrag){0.f,0.f,0.f,0.f}; C2[0][1]=(ffrag){0.f,0.f,0.f,0.f};
      C2[1][0]=(ffrag){0.f,0.f,0.f,0.f}; C2[1][1]=(ffrag){0.f,0.f,0.f,0.f};
      #pragma unroll
      for (int s=0;s<8;s++) {
        bfrag A0 = *(const bfrag*)&s_hp[l15*264      + s*32 + quad*8];
        bfrag A1 = *(const bfrag*)&s_hp[(16+l15)*264 + s*32 + quad*8];
        bfrag B0 = *(const bfrag*)&w2t[l15*256      + s*32 + quad*8];
        bfrag B1 = *(const bfrag*)&w2t[(16+l15)*256 + s*32 + quad*8];
        C2[0][0] = __builtin_amdgcn_mfma_f32_16x16x32_bf16(A0, B0, C2[0][0], 0, 0, 0);
        C2[0][1] = __builtin_amdgcn_mfma_f32_16x16x32_bf16(A0, B1, C2[0][1], 0, 0, 0);
        C2[1][0] = __builtin_amdgcn_mfma_f32_16x16x32_bf16(A1, B0, C2[1][0], 0, 0, 0);
        C2[1][1] = __builtin_amdgcn_mfma_f32_16x16x32_bf16(A1, B1, C2[1][1], 0, 0, 0);
      }
      #pragma unroll
      for (int qs=0;qs<2;qs++)
        #pragma unroll
        for (int et=0;et<2;et++)
          #pragma unroll
          for (int r=0;r<4;r++) {
            float es = fmaf(C2[qs][et][r], LOG2E, et ? bq2s1 : bq2s0);
            s_eq[(qs*16+quad*4+r)*40 + et*16 + l15] = (__bf16)es;
          }
    }
    // ---- phase 3: mask + logits + softmax, entirely intra-wave ----
    bfrag Bq0 = *(const bfrag*)&s_eq[l15*40      + quad*8];
    bfrag Bq1 = *(const bfrag*)&s_eq[(16+l15)*40 + quad*8];
    float msum0 = 0.f, msum1 = 0.f;
    #pragma unroll
    for (int ut=0; ut<4; ut++) {
      bfrag Aw = *(const bfrag*)&wa1t[(ut*16+l15)*32 + quad*8];
      ffrag Cm0 = {0.f,0.f,0.f,0.f}, Cm1 = {0.f,0.f,0.f,0.f};
      Cm0 = __builtin_amdgcn_mfma_f32_16x16x32_bf16(Aw, Bq0, Cm0, 0, 0, 0);
      Cm1 = __builtin_amdgcn_mfma_f32_16x16x32_bf16(Aw, Bq1, Cm1, 0, 0, 0);
      float4 bav = *(const float4*)&ba1[ut*16 + quad*4];
      float4 wav = *(const float4*)&Wa2[ut*16 + quad*4];
      msum0 = fmaf(fmaxf(Cm0[0]+bav.x,0.f), wav.x, msum0);
      msum0 = fmaf(fmaxf(Cm0[1]+bav.y,0.f), wav.y, msum0);
      msum0 = fmaf(fmaxf(Cm0[2]+bav.z,0.f), wav.z, msum0);
      msum0 = fmaf(fmaxf(Cm0[3]+bav.w,0.f), wav.w, msum0);
      msum1 = fmaf(fmaxf(Cm1[0]+bav.x,0.f), wav.x, msum1);
      msum1 = fmaf(fmaxf(Cm1[1]+bav.y,0.f), wav.y, msum1);
      msum1 = fmaf(fmaxf(Cm1[2]+bav.z,0.f), wav.z, msum1);
      msum1 = fmaf(fmaxf(Cm1[3]+bav.w,0.f), wav.w, msum1);
    }
    msum0 += __shfl_xor(msum0, 16); msum0 += __shfl_xor(msum0, 32);
    msum1 += __shfl_xor(msum1, 16); msum1 += __shfl_xor(msum1, 32);
    float rs0, rs1;
    #pragma unroll
    for (int qs=0;qs<2;qs++) {
      const bfrag Bq = qs ? Bq1 : Bq0;
      ffrag Sv[16];
      float mx = -1e30f;
      #pragma unroll
      for (int t=0;t<16;t++) {
        bfrag Ae = *(const bfrag*)&eo[(t*16+l15)*32 + quad*8];
        ffrag S = {0.f,0.f,0.f,0.f};
        S = __builtin_amdgcn_mfma_f32_16x16x32_bf16(Ae, Bq, S, 0, 0, 0);
        Sv[t] = S;
        mx = fmaxf(mx, fmaxf(fmaxf(S[0], S[1]), fmaxf(S[2], S[3])));
      }
      mx = fmaxf(mx, __shfl_xor(mx, 16));
      mx = fmaxf(mx, __shfl_xor(mx, 32));
      float ps = 0.f;
      #pragma unroll
      for (int t=0;t<16;t++) {
        __bf16 p[4] __attribute__((aligned(8)));
        #pragma unroll
        for (int r=0;r<4;r++) {
          float e = exp2f(Sv[t][r] - mx);    // logits are log2e-scaled -> native v_exp
          ps += e;
          p[r] = (__bf16)e;
        }
        *(uint2*)&s_hp[(qs*16+l15)*264 + t*16 + quad*4] = *(const uint2*)p;
      }
      ps += __shfl_xor(ps, 16); ps += __shfl_xor(ps, 32);
      float rsv = sigmoidf_((qs ? msum1 : msum0) + ba2v) / ps;
      if (qs == 0) rs0 = rsv; else rs1 = rsv;
    }
    // ---- phase 4: vatt D[c][q] = V^T @ P^T, full 128 c, 2 ct-groups of 4 ----
    #pragma unroll
    for (int g=0; g<2; g++) {
      ffrag Cv[4][2];
      #pragma unroll
      for (int c4=0;c4<4;c4++) {
        Cv[c4][0] = (ffrag){0.f,0.f,0.f,0.f};
        Cv[c4][1] = (ffrag){0.f,0.f,0.f,0.f};
      }
      #pragma unroll
      for (int s=0;s<8;s++) {
        bfrag Bp0 = *(const bfrag*)&s_hp[l15*264      + s*32 + quad*8];
        bfrag Bp1 = *(const bfrag*)&s_hp[(16+l15)*264 + s*32 + quad*8];
        #pragma unroll
        for (int c4=0;c4<4;c4++) {
          int ct = g*4 + c4;
          bfrag Av;
          if (PRE) {
            Av = *(const bfrag*)&vbf[((size_t)bn<<15) + (ct*16+l15)*256 + s*32 + quad*8];
          } else {
            const float* p0 = &vc[((size_t)bn<<15) + (ct*16+l15)*256 + s*32 + quad*8];
            float4 a0 = *(const float4*)p0, a1 = *(const float4*)(p0+4);
            Av[0]=(__bf16)a0.x; Av[1]=(__bf16)a0.y; Av[2]=(__bf16)a0.z; Av[3]=(__bf16)a0.w;
            Av[4]=(__bf16)a1.x; Av[5]=(__bf16)a1.y; Av[6]=(__bf16)a1.z; Av[7]=(__bf16)a1.w;
          }
          Cv[c4][0] = __builtin_amdgcn_mfma_f32_16x16x32_bf16(Av, Bp0, Cv[c4][0], 0, 0, 0);
          Cv[c4][1] = __builtin_amdgcn_mfma_f32_16x16x32_bf16(Av, Bp1, Cv[c4][1], 0, 0, 0);
        }
      }
      #pragma unroll
      for (int c4=0;c4<4;c4++)
        #pragma unroll
        for (int r=0;r<4;r++) {
          acc[g*4+c4][0][r] = fmaf(rs0, Cv[c4][0][r], acc[g*4+c4][0][r]);
          acc[g*4+c4][1][r] = fmaf(rs1, Cv[c4][1][r], acc[g*4+c4][1][r]);
        }
    }
  }
  // ---- epilogue: direct coalesced stores (16 lanes consecutive q = 64 B) ----
  #pragma unroll
  for (int ct=0;ct<8;ct++) {
    #pragma unroll
    for (int qs=0;qs<2;qs++) {
      #pragma unroll
      for (int r=0;r<4;r++) {
        int c = ct*16 + quad*4 + r;
        out[(size_t)b*196608 + (size_t)c*1536 + qt0 + qs*16 + l15] = sigmoidf_(acc[ct][qs][r]);
      }
    }
  }
}

extern "C" void kernel_launch(void* const* d_in, const int* in_sizes, int n_in,
                              void* d_out, int out_size, void* d_ws, size_t ws_size,
                              hipStream_t stream) {
  const float* view_cell = (const float*)d_in[0];
  const float* pose_o = (const float*)d_in[1];
  const float* pose_q = (const float*)d_in[2];
  const float* Wk1 = (const float*)d_in[3];
  const float* bk1 = (const float*)d_in[4];
  const float* Wk2 = (const float*)d_in[5];
  const float* bk2 = (const float*)d_in[6];
  const float* Wq1 = (const float*)d_in[7];
  const float* bq1 = (const float*)d_in[8];
  const float* Wq2 = (const float*)d_in[9];
  const float* bq2 = (const float*)d_in[10];
  const float* Wa1 = (const float*)d_in[11];
  const float* ba1 = (const float*)d_in[12];
  const float* Wa2 = (const float*)d_in[13];
  const float* ba2 = (const float*)d_in[14];

  float* out = (float*)d_out;
  float* out_qo = out + 6291456;
  float* out_qq = out + 6291456 + 1792;

  bf16* ws_eo   = (bf16*)((char*)d_ws + WS_EO);
  bf16* ws_w2t  = (bf16*)((char*)d_ws + WS_W2T);
  bf16* ws_w1t  = (bf16*)((char*)d_ws + WS_W1T);
  bf16* ws_wa1t = (bf16*)((char*)d_ws + WS_WA1T);
  bf16* ws_vbf  = (bf16*)((char*)d_ws + WS_VBF);

  const bool pre = ws_size >= (size_t)(WS_VBF + 256u*128u*256u*2u);
  const int vblocks = pre ? 4096 : 0;

  hipLaunchKernelGGL(k_prep, dim3(vblocks + 5), dim3(256), 0, stream,
                     view_cell, ws_vbf, pose_o, pose_q, Wk1, bk1, Wk2, bk2,
                     Wq1, bq1, Wq2, Wa1, out_qo, out_qq,
                     ws_eo, ws_w2t, ws_w1t, ws_wa1t, vblocks);

  if (pre) {
    hipLaunchKernelGGL((k_main<true>), dim3(1536), dim3(64), 0, stream,
                       view_cell, ws_vbf, pose_o, pose_q, ws_eo, ws_w2t,
                       ws_w1t, ws_wa1t, bq2, ba1, Wa2, ba2, out);
  } else {
    hipLaunchKernelGGL((k_main<false>), dim3(1536), dim3(64), 0, stream,
                       view_cell, ws_vbf, pose_o, pose_q, ws_eo, ws_w2t,
                       ws_w1t, ws_wa1t, bq2, ba1, Wa2, ba2, out);
  }
}